// Round 17
// baseline (194.817 us; speedup 1.0000x reference)
//
#include <hip/hip_runtime.h>
#include <stdint.h>

#define Bb 4
#define Tt 2048
#define Dd 1024
#define Hh 16
#define HDd 64
#define Mm 8192   // Bb*Tt

typedef __attribute__((ext_vector_type(8))) short bf16x8;
typedef __attribute__((ext_vector_type(4))) float f32x4;
typedef __attribute__((ext_vector_type(16))) float f32x16;

#define MFMA(a, b, c) __builtin_amdgcn_mfma_f32_16x16x32_bf16(a, b, c, 0, 0, 0)
#define MFMA32(a, b, c) __builtin_amdgcn_mfma_f32_32x32x16_bf16(a, b, c, 0, 0, 0)

#define LOG2E 1.44269504088896340736f
#if __has_builtin(__builtin_amdgcn_exp2f)
#define EXP2(x) __builtin_amdgcn_exp2f(x)
#else
#define EXP2(x) __expf((x) * 0.69314718055994530942f)
#endif

union vfu { uint2 u2[2]; bf16x8 v; };
union apu { uint32_t u[4]; bf16x8 v; };

__device__ __forceinline__ unsigned short f2b(float f) {
  union { float f; uint32_t u; } v; v.f = f;
  return (unsigned short)((v.u + 0x7FFFu + ((v.u >> 16) & 1u)) >> 16);
}

// pack two f32 -> bf16x2 (compiler emits v_cvt_pk_bf16_f32)
__device__ __forceinline__ uint32_t pk2(float a, float b) {
  union { __bf16 h[2]; uint32_t u; } x;
  x.h[0] = (__bf16)a; x.h[1] = (__bf16)b;
  return x.u;
}

__device__ __forceinline__ void gload_lds16(const void* g, void* l) {
  __builtin_amdgcn_global_load_lds(
      (const __attribute__((address_space(1))) void*)g,
      (__attribute__((address_space(3))) void*)l, 16, 0, 0);
}

// ---------------- x f32 -> bf16 ----------------
__global__ __launch_bounds__(256) void k_convert_x(const float* __restrict__ x,
                                                   unsigned short* __restrict__ xb) {
  int i = (blockIdx.x * 256 + threadIdx.x) * 8;
  float4 a = *(const float4*)(x + i);
  float4 b = *(const float4*)(x + i + 4);
  uint4 o;
  o.x = f2b(a.x) | ((uint32_t)f2b(a.y) << 16);
  o.y = f2b(a.z) | ((uint32_t)f2b(a.w) << 16);
  o.z = f2b(b.x) | ((uint32_t)f2b(b.y) << 16);
  o.w = f2b(b.z) | ((uint32_t)f2b(b.w) << 16);
  *(uint4*)(xb + i) = o;
}

// ---------------- W [K][N] f32 -> Wt [N][K] bf16 ----------------
__global__ __launch_bounds__(256) void k_transpose_w(
    const float* __restrict__ Wk, const float* __restrict__ Wq,
    const float* __restrict__ Wv, const float* __restrict__ Wp,
    unsigned short* __restrict__ WkT, unsigned short* __restrict__ WqT,
    unsigned short* __restrict__ WvT, unsigned short* __restrict__ WpT) {
  const float* W; unsigned short* O;
  int wsel = blockIdx.y;
  W = wsel == 0 ? Wk : wsel == 1 ? Wq : wsel == 2 ? Wv : Wp;
  O = wsel == 0 ? WkT : wsel == 1 ? WqT : wsel == 2 ? WvT : WpT;
  __shared__ unsigned short tile[32][36];
  int kb = (blockIdx.x >> 5) << 5;
  int nb = (blockIdx.x & 31) << 5;
  int t = threadIdx.x;
  int r = t >> 3, c4 = (t & 7) << 2;
  float4 v = *(const float4*)(W + (size_t)(kb + r) * Dd + nb + c4);
  tile[r][c4 + 0] = f2b(v.x); tile[r][c4 + 1] = f2b(v.y);
  tile[r][c4 + 2] = f2b(v.z); tile[r][c4 + 3] = f2b(v.w);
  __syncthreads();
  uint2 o;
  o.x = tile[c4 + 0][r] | ((uint32_t)tile[c4 + 1][r] << 16);
  o.y = tile[c4 + 2][r] | ((uint32_t)tile[c4 + 3][r] << 16);
  *(uint2*)(O + (size_t)(nb + r) * Dd + kb + c4) = o;
}

// ---------------- fused QKV GEMM: xb @ {Wq,Wk,Wv}^T + bias ----------------
__global__ __launch_bounds__(256, 2) void k_gemm3(
    const unsigned short* __restrict__ A,
    const unsigned short* __restrict__ BtQ, const unsigned short* __restrict__ BtK,
    const unsigned short* __restrict__ BtV,
    const float* __restrict__ bq, const float* __restrict__ bk,
    const float* __restrict__ bv,
    unsigned short* __restrict__ Qb, unsigned short* __restrict__ Kb,
    unsigned short* __restrict__ VTb) {
  __shared__ __align__(16) unsigned short Al[128 * 32];
  __shared__ __align__(16) unsigned short Bl[3][128 * 32];
  int tid = threadIdx.x;
  int lane = tid & 63, wid = tid >> 6;
  int wr = wid >> 1, wc = wid & 1;
  int lq = lane & 15, lh = lane >> 4;
  int mb = blockIdx.x * 128;
  int nb = blockIdx.y << 7;

  int srow = (wid << 5) + (lane >> 2);
  int scol = (lane & 3) << 3;
  const unsigned short* Ag = A + (size_t)(mb + srow) * Dd + scol;
  const unsigned short* Bg0 = BtQ + (size_t)(nb + srow) * Dd + scol;
  const unsigned short* Bg1 = BtK + (size_t)(nb + srow) * Dd + scol;
  const unsigned short* Bg2 = BtV + (size_t)(nb + srow) * Dd + scol;
  unsigned short* Alw = Al + (wid << 10);
  unsigned short* Blw0 = &Bl[0][0] + (wid << 10);
  unsigned short* Blw1 = &Bl[1][0] + (wid << 10);
  unsigned short* Blw2 = &Bl[2][0] + (wid << 10);

  f32x4 zero = {0.f, 0.f, 0.f, 0.f};
  f32x4 acc[3][4][4];
#pragma unroll
  for (int s = 0; s < 3; s++)
#pragma unroll
    for (int m = 0; m < 4; m++)
#pragma unroll
      for (int n = 0; n < 4; n++) acc[s][m][n] = zero;

  for (int kb = 0; kb < Dd; kb += 32) {
    __syncthreads();
    gload_lds16(Ag + kb, Alw);
    gload_lds16(Ag + kb + 16 * Dd, Alw + 16 * 32);
    gload_lds16(Bg0 + kb, Blw0);
    gload_lds16(Bg0 + kb + 16 * Dd, Blw0 + 16 * 32);
    gload_lds16(Bg1 + kb, Blw1);
    gload_lds16(Bg1 + kb + 16 * Dd, Blw1 + 16 * 32);
    gload_lds16(Bg2 + kb, Blw2);
    gload_lds16(Bg2 + kb + 16 * Dd, Blw2 + 16 * 32);
    __syncthreads();
    bf16x8 af[4];
#pragma unroll
    for (int m = 0; m < 4; m++)
      af[m] = *(const bf16x8*)(Al + (((wr << 6) + (m << 4) + lq) << 5) + (lh << 3));
#pragma unroll
    for (int s = 0; s < 3; s++) {
      bf16x8 bf[4];
#pragma unroll
      for (int n = 0; n < 4; n++)
        bf[n] = *(const bf16x8*)(&Bl[s][0] +
                                 (((wc << 6) + (n << 4) + lq) << 5) + (lh << 3));
      __builtin_amdgcn_s_setprio(1);
#pragma unroll
      for (int m = 0; m < 4; m++)
#pragma unroll
        for (int n = 0; n < 4; n++) acc[s][m][n] = MFMA(af[m], bf[n], acc[s][m][n]);
      __builtin_amdgcn_s_setprio(0);
    }
  }

  int b_idx = mb >> 11;
#pragma unroll
  for (int s = 0; s < 3; s++) {
#pragma unroll
    for (int n = 0; n < 4; n++) {
      int col = nb + (wc << 6) + (n << 4) + lq;
      float bbias = (s == 0) ? bq[col] : (s == 1) ? bk[col] : bv[col];
      int hh = col >> 6, hd = col & 63;
#pragma unroll
      for (int m = 0; m < 4; m++) {
        int row0 = mb + (wr << 6) + (m << 4) + (lh << 2);
        int t0 = row0 & 2047;
        if (s == 2) {          // V -> [B,H,64,T], t-swizzled
          float v0 = acc[s][m][n][0] + bbias, v1 = acc[s][m][n][1] + bbias;
          float v2 = acc[s][m][n][2] + bbias, v3 = acc[s][m][n][3] + bbias;
          uint2 pv;
          pv.x = f2b(v0) | ((uint32_t)f2b(v1) << 16);
          pv.y = f2b(v2) | ((uint32_t)f2b(v3) << 16);
          int t0s = t0 ^ ((hd & 7) << 3);
          *(uint2*)(VTb + ((size_t)(b_idx * 16 + hh) * 64 + hd) * Tt + t0s) = pv;
        } else {               // Q (scaled) / K (row-swizzled) -> [B,H,T,64]
          unsigned short* O = (s == 0) ? Qb : Kb;
          float sc = (s == 0) ? (0.125f * LOG2E) : 1.0f;
#pragma unroll
          for (int r = 0; r < 4; r++) {
            float v = (acc[s][m][n][r] + bbias) * sc;
            int trow = t0 + r;
            int hds = (s == 0) ? hd : (hd ^ ((trow & 7) << 3));
            O[((size_t)(b_idx * 16 + hh) * Tt + trow) * 64 + hds] = f2b(v);
          }
        }
      }
    }
  }
}

// ---------------- GEMM (projection): A[M][1024] bf16 @ Bt^T + bias -> f32 ----
__global__ __launch_bounds__(256) void k_gemm(
    const unsigned short* __restrict__ A,
    const unsigned short* __restrict__ Bt0,
    const float* __restrict__ bias0,
    float* __restrict__ Pout) {
  __shared__ __align__(16) unsigned short Al[128 * 32];
  __shared__ __align__(16) unsigned short Bl[128 * 32];
  int tid = threadIdx.x;
  int lane = tid & 63, wid = tid >> 6;
  int wr = wid >> 1, wc = wid & 1;
  int lq = lane & 15, lh = lane >> 4;
  int mb = blockIdx.x * 128;
  int nb = blockIdx.y << 7;
  const unsigned short* Bt = Bt0; const float* bias = bias0;

  int srow = (wid << 5) + (lane >> 2);
  int scol = (lane & 3) << 3;
  const unsigned short* Ag = A + (size_t)(mb + srow) * Dd + scol;
  const unsigned short* Bg = Bt + (size_t)(nb + srow) * Dd + scol;
  unsigned short* Alw = Al + (wid << 10);
  unsigned short* Blw = Bl + (wid << 10);

  f32x4 zero = {0.f, 0.f, 0.f, 0.f};
  f32x4 acc[4][4];
#pragma unroll
  for (int m = 0; m < 4; m++)
#pragma unroll
    for (int n = 0; n < 4; n++) acc[m][n] = zero;

  for (int kb = 0; kb < Dd; kb += 32) {
    __syncthreads();
    gload_lds16(Ag + kb, Alw);
    gload_lds16(Ag + kb + 16 * Dd, Alw + 16 * 32);
    gload_lds16(Bg + kb, Blw);
    gload_lds16(Bg + kb + 16 * Dd, Blw + 16 * 32);
    __syncthreads();
    bf16x8 af[4], bf[4];
#pragma unroll
    for (int m = 0; m < 4; m++)
      af[m] = *(const bf16x8*)(Al + (((wr << 6) + (m << 4) + lq) << 5) + (lh << 3));
#pragma unroll
    for (int n = 0; n < 4; n++)
      bf[n] = *(const bf16x8*)(Bl + (((wc << 6) + (n << 4) + lq) << 5) + (lh << 3));
#pragma unroll
    for (int m = 0; m < 4; m++)
#pragma unroll
      for (int n = 0; n < 4; n++) acc[m][n] = MFMA(af[m], bf[n], acc[m][n]);
  }

#pragma unroll
  for (int n = 0; n < 4; n++) {
    int col = nb + (wc << 6) + (n << 4) + lq;
    float bb = bias[col];
#pragma unroll
    for (int m = 0; m < 4; m++) {
      int row0 = mb + (wr << 6) + (m << 4) + (lh << 2);
#pragma unroll
      for (int r = 0; r < 4; r++)
        Pout[(size_t)(row0 + r) * Dd + col] = acc[m][n][r] + bb;
    }
  }
}

// ---------------- flash attention (causal), Q pre-scaled by 0.125*log2e ----------
// r12 structure (best measured: 75us) + register diet: exp->lsum->pk2 fused in
// one pass (kills the pA[16]/pB[16] live ranges, ~28 regs) so unified demand
// fits the 170-reg cap of __launch_bounds__(256,3) -> 3 waves/SIMD instead of 2.
// Block = 4 waves x 64q = 256 q rows; grid 512, complement-paired qt, XCD-keyed bh.
__global__ __launch_bounds__(256, 3) void k_attn(
    const unsigned short* __restrict__ Qb, const unsigned short* __restrict__ Kb,
    const unsigned short* __restrict__ VTb, unsigned short* __restrict__ yb) {
  __shared__ __align__(16) unsigned short KL[2][4096];
  __shared__ __align__(16) unsigned short VL[2][4096];
  int b = blockIdx.x;
  int qt = (b < 256) ? (7 - (b >> 6)) : ((b - 256) >> 6);
  int rr6 = b & 63;
  int bh = ((rr6 & 7) << 3) | (rr6 >> 3);    // XCD x holds heads 8x..8x+7
  int tid = threadIdx.x, lane = tid & 63, w = tid >> 6;
  int l31 = lane & 31, hi = lane >> 5;
  const unsigned short* __restrict__ Qh = Qb + (size_t)bh * Tt * 64;
  const unsigned short* __restrict__ Kh = Kb + (size_t)bh * Tt * 64;
  const unsigned short* __restrict__ Vh = VTb + (size_t)bh * 64 * Tt;
  int qgA = (qt << 8) + (w << 6);            // wave's 64 q rows (two halves)
  int qgB = qgA + 32;

  bf16x8 qfA[4], qfB[4];
#pragma unroll
  for (int c = 0; c < 4; c++) {
    qfA[c] = *(const bf16x8*)(Qh + (size_t)(qgA + l31) * 64 + (c << 4) + (hi << 3));
    qfB[c] = *(const bf16x8*)(Qh + (size_t)(qgB + l31) * 64 + (c << 4) + (hi << 3));
  }

  f32x16 accA0, accA1, accB0, accB1;
#pragma unroll
  for (int i = 0; i < 16; i++) { accA0[i] = 0.f; accA1[i] = 0.f; accB0[i] = 0.f; accB1[i] = 0.f; }
  float lsumA = 0.f, lsumB = 0.f;

  int jmaxb = (qt << 2) + 3;   // block's last kv tile (wave 3 half-B diagonal)
  int srow = lane >> 3, scol = (lane & 7) << 3;
  int rowb = w << 4;           // wave stages 16 rows of K and of V per tile
  int swz = l31 & 7;

#define STAGE(kvt_, bi_) do {                                                       \
    int kv_ = (kvt_) << 6;                                                          \
    gload_lds16(Kh + (size_t)(kv_ + rowb + srow) * 64 + scol, &KL[bi_][rowb << 6]); \
    gload_lds16(Kh + (size_t)(kv_ + rowb + 8 + srow) * 64 + scol,                   \
                &KL[bi_][(rowb + 8) << 6]);                                         \
    gload_lds16(Vh + (size_t)(rowb + srow) * Tt + kv_ + scol, &VL[bi_][rowb << 6]); \
    gload_lds16(Vh + (size_t)(rowb + 8 + srow) * Tt + kv_ + scol,                   \
                &VL[bi_][(rowb + 8) << 6]);                                         \
  } while (0)

  STAGE(0, 0);
  __syncthreads();

  int cur = 0;
  for (int jt = 0; jt <= jmaxb; ++jt) {
    if (jt < jmaxb) STAGE(jt + 1, cur ^ 1);
    int kv0 = jt << 6;
    int dA = qgA - kv0;    // wave-uniform, multiple of 64
    if (dA >= 0) {
      const unsigned short* KB = &KL[cur][0];
      const unsigned short* VB = &VL[cur][0];
      bool dg = (dA == 0);
      int relA = dA + l31, relB = relA + 32;
#pragma unroll
      for (int n2 = 0; n2 < 2; n2++) {
        bf16x8 kf[4];
        int krowb = ((n2 << 5) + l31) << 6;
#pragma unroll
        for (int c = 0; c < 4; c++)
          kf[c] = *(const bf16x8*)(KB + krowb + ((((c << 1) + hi) ^ swz) << 3));
        f32x16 sA, sB;
#pragma unroll
        for (int i = 0; i < 16; i++) { sA[i] = 0.f; sB[i] = 0.f; }
        __builtin_amdgcn_s_setprio(1);
#pragma unroll
        for (int c = 0; c < 4; c++) {
          sA = MFMA32(kf[c], qfA[c], sA);
          sB = MFMA32(kf[c], qfB[c], sB);
        }
        __builtin_amdgcn_s_setprio(0);
        // fused exp -> lsum -> pack (no pA/pB arrays: short live ranges)
        apu a0, a1, b0, b1;
        if (dg) {
#pragma unroll
          for (int g = 0; g < 8; g++) {
            int r0 = 2 * g, r1 = 2 * g + 1;
            int k0 = (n2 << 5) + (r0 & 3) + ((r0 >> 2) << 3) + (hi << 2);
            int k1 = k0 + 1;  // r1 = r0+1 within same quad: krow increments by 1
            float p0 = EXP2(k0 > relA ? -1e30f : sA[r0]);
            float p1 = EXP2(k1 > relA ? -1e30f : sA[r1]);
            float q0 = EXP2(k0 > relB ? -1e30f : sB[r0]);
            float q1 = EXP2(k1 > relB ? -1e30f : sB[r1]);
            lsumA += p0 + p1;
            lsumB += q0 + q1;
            if (g < 4) { a0.u[g] = pk2(p0, p1); b0.u[g] = pk2(q0, q1); }
            else       { a1.u[g - 4] = pk2(p0, p1); b1.u[g - 4] = pk2(q0, q1); }
          }
        } else {
#pragma unroll
          for (int g = 0; g < 8; g++) {
            int r0 = 2 * g, r1 = 2 * g + 1;
            float p0 = EXP2(sA[r0]);
            float p1 = EXP2(sA[r1]);
            float q0 = EXP2(sB[r0]);
            float q1 = EXP2(sB[r1]);
            lsumA += p0 + p1;
            lsumB += q0 + q1;
            if (g < 4) { a0.u[g] = pk2(p0, p1); b0.u[g] = pk2(q0, q1); }
            else       { a1.u[g - 4] = pk2(p0, p1); b1.u[g - 4] = pk2(q0, q1); }
          }
        }
        vfu vf[2][2];
#pragma unroll
        for (int n2v = 0; n2v < 2; n2v++) {
          int vrowb = ((n2v << 5) + l31) << 6;
#pragma unroll
          for (int cc = 0; cc < 2; cc++) {
            int blk0 = (n2 << 2) + (cc << 1);
            vf[n2v][cc].u2[0] =
                *(const uint2*)(VB + vrowb + ((blk0 ^ swz) << 3) + (hi << 2));
            vf[n2v][cc].u2[1] =
                *(const uint2*)(VB + vrowb + (((blk0 + 1) ^ swz) << 3) + (hi << 2));
          }
        }
        __builtin_amdgcn_s_setprio(1);
        accA0 = MFMA32(a0.v, vf[0][0].v, accA0);
        accA1 = MFMA32(a0.v, vf[1][0].v, accA1);
        accB0 = MFMA32(b0.v, vf[0][0].v, accB0);
        accB1 = MFMA32(b0.v, vf[1][0].v, accB1);
        accA0 = MFMA32(a1.v, vf[0][1].v, accA0);
        accA1 = MFMA32(a1.v, vf[1][1].v, accA1);
        accB0 = MFMA32(b1.v, vf[0][1].v, accB0);
        accB1 = MFMA32(b1.v, vf[1][1].v, accB1);
        __builtin_amdgcn_s_setprio(0);
      }
    }
    __syncthreads();
    cur ^= 1;
  }
#undef STAGE

  lsumA += __shfl_xor(lsumA, 32);
  lsumB += __shfl_xor(lsumB, 32);
  float invA = 1.0f / lsumA;
  float invB = 1.0f / lsumB;
  int bb = bh >> 4, hh = bh & 15;
#pragma unroll
  for (int r = 0; r < 16; r++) {
    int qr = (r & 3) + ((r >> 2) << 3) + (hi << 2);
    float invqA = __shfl(invA, qr);
    float invqB = __shfl(invB, qr);
    size_t baseA = ((size_t)(bb * Tt + qgA + qr)) * Dd + (hh << 6) + l31;
    size_t baseB = ((size_t)(bb * Tt + qgB + qr)) * Dd + (hh << 6) + l31;
    yb[baseA] = f2b(accA0[r] * invqA);
    yb[baseA + 32] = f2b(accA1[r] * invqA);
    yb[baseB] = f2b(accB0[r] * invqB);
    yb[baseB + 32] = f2b(accB1[r] * invqB);
  }
}

extern "C" void kernel_launch(void* const* d_in, const int* in_sizes, int n_in,
                              void* d_out, int out_size, void* d_ws, size_t ws_size,
                              hipStream_t stream) {
  const float* x = (const float*)d_in[0];
  const float* Wk = (const float*)d_in[1];
  const float* bk = (const float*)d_in[2];
  const float* Wq = (const float*)d_in[3];
  const float* bq = (const float*)d_in[4];
  const float* Wv = (const float*)d_in[5];
  const float* bv = (const float*)d_in[6];
  const float* Wp = (const float*)d_in[7];
  const float* bp = (const float*)d_in[8];
  float* out = (float*)d_out;

  char* ws = (char*)d_ws;
  unsigned short* xb  = (unsigned short*)(ws);                       // 16MB
  unsigned short* WkT = (unsigned short*)(ws + (16ull << 20));       // 2MB each
  unsigned short* WqT = (unsigned short*)(ws + (18ull << 20));
  unsigned short* WvT = (unsigned short*)(ws + (20ull << 20));
  unsigned short* WpT = (unsigned short*)(ws + (22ull << 20));
  unsigned short* Qb  = (unsigned short*)(ws + (24ull << 20));       // 16MB
  unsigned short* Kb  = (unsigned short*)(ws + (40ull << 20));       // 16MB
  unsigned short* VTb = (unsigned short*)(ws + (56ull << 20));       // 16MB
  unsigned short* yb  = (unsigned short*)(ws + (72ull << 20));       // 16MB (ends 88MB)

  k_convert_x<<<4096, 256, 0, stream>>>(x, xb);
  k_transpose_w<<<dim3(1024, 4), 256, 0, stream>>>(Wk, Wq, Wv, Wp, WkT, WqT, WvT, WpT);
  k_gemm3<<<dim3(64, 8), 256, 0, stream>>>(xb, WqT, WkT, WvT, bq, bk, bv,
                                           Qb, Kb, VTb);
  k_attn<<<512, 256, 0, stream>>>(Qb, Kb, VTb, yb);
  k_gemm<<<dim3(64, 8), 256, 0, stream>>>(yb, WpT, bp, out);
}

// Round 18
// 159.770 us; speedup vs baseline: 1.2194x; 1.2194x over previous
//
#include <hip/hip_runtime.h>
#include <stdint.h>

#define Bb 4
#define Tt 2048
#define Dd 1024
#define Hh 16
#define HDd 64
#define Mm 8192   // Bb*Tt

typedef __attribute__((ext_vector_type(8))) short bf16x8;
typedef __attribute__((ext_vector_type(4))) float f32x4;
typedef __attribute__((ext_vector_type(16))) float f32x16;

#define MFMA(a, b, c) __builtin_amdgcn_mfma_f32_16x16x32_bf16(a, b, c, 0, 0, 0)
#define MFMA32(a, b, c) __builtin_amdgcn_mfma_f32_32x32x16_bf16(a, b, c, 0, 0, 0)

#define LOG2E 1.44269504088896340736f
#if __has_builtin(__builtin_amdgcn_exp2f)
#define EXP2(x) __builtin_amdgcn_exp2f(x)
#else
#define EXP2(x) __expf((x) * 0.69314718055994530942f)
#endif

union vfu { uint2 u2[2]; bf16x8 v; };
union apu { uint32_t u[4]; bf16x8 v; };

__device__ __forceinline__ unsigned short f2b(float f) {
  union { float f; uint32_t u; } v; v.f = f;
  return (unsigned short)((v.u + 0x7FFFu + ((v.u >> 16) & 1u)) >> 16);
}

// pack two f32 -> bf16x2 (compiler emits v_cvt_pk_bf16_f32)
__device__ __forceinline__ uint32_t pk2(float a, float b) {
  union { __bf16 h[2]; uint32_t u; } x;
  x.h[0] = (__bf16)a; x.h[1] = (__bf16)b;
  return x.u;
}

__device__ __forceinline__ void gload_lds16(const void* g, void* l) {
  __builtin_amdgcn_global_load_lds(
      (const __attribute__((address_space(1))) void*)g,
      (__attribute__((address_space(3))) void*)l, 16, 0, 0);
}

// ---------------- x f32 -> bf16 ----------------
__global__ __launch_bounds__(256) void k_convert_x(const float* __restrict__ x,
                                                   unsigned short* __restrict__ xb) {
  int i = (blockIdx.x * 256 + threadIdx.x) * 8;
  float4 a = *(const float4*)(x + i);
  float4 b = *(const float4*)(x + i + 4);
  uint4 o;
  o.x = f2b(a.x) | ((uint32_t)f2b(a.y) << 16);
  o.y = f2b(a.z) | ((uint32_t)f2b(a.w) << 16);
  o.z = f2b(b.x) | ((uint32_t)f2b(b.y) << 16);
  o.w = f2b(b.z) | ((uint32_t)f2b(b.w) << 16);
  *(uint4*)(xb + i) = o;
}

// ---------------- W [K][N] f32 -> Wt [N][K] bf16 ----------------
__global__ __launch_bounds__(256) void k_transpose_w(
    const float* __restrict__ Wk, const float* __restrict__ Wq,
    const float* __restrict__ Wv, const float* __restrict__ Wp,
    unsigned short* __restrict__ WkT, unsigned short* __restrict__ WqT,
    unsigned short* __restrict__ WvT, unsigned short* __restrict__ WpT) {
  const float* W; unsigned short* O;
  int wsel = blockIdx.y;
  W = wsel == 0 ? Wk : wsel == 1 ? Wq : wsel == 2 ? Wv : Wp;
  O = wsel == 0 ? WkT : wsel == 1 ? WqT : wsel == 2 ? WvT : WpT;
  __shared__ unsigned short tile[32][36];
  int kb = (blockIdx.x >> 5) << 5;
  int nb = (blockIdx.x & 31) << 5;
  int t = threadIdx.x;
  int r = t >> 3, c4 = (t & 7) << 2;
  float4 v = *(const float4*)(W + (size_t)(kb + r) * Dd + nb + c4);
  tile[r][c4 + 0] = f2b(v.x); tile[r][c4 + 1] = f2b(v.y);
  tile[r][c4 + 2] = f2b(v.z); tile[r][c4 + 3] = f2b(v.w);
  __syncthreads();
  uint2 o;
  o.x = tile[c4 + 0][r] | ((uint32_t)tile[c4 + 1][r] << 16);
  o.y = tile[c4 + 2][r] | ((uint32_t)tile[c4 + 3][r] << 16);
  *(uint2*)(O + (size_t)(nb + r) * Dd + kb + c4) = o;
}

// ---------------- fused QKV GEMM: xb @ {Wq,Wk,Wv}^T + bias ----------------
__global__ __launch_bounds__(256, 2) void k_gemm3(
    const unsigned short* __restrict__ A,
    const unsigned short* __restrict__ BtQ, const unsigned short* __restrict__ BtK,
    const unsigned short* __restrict__ BtV,
    const float* __restrict__ bq, const float* __restrict__ bk,
    const float* __restrict__ bv,
    unsigned short* __restrict__ Qb, unsigned short* __restrict__ Kb,
    unsigned short* __restrict__ VTb) {
  __shared__ __align__(16) unsigned short Al[128 * 32];
  __shared__ __align__(16) unsigned short Bl[3][128 * 32];
  int tid = threadIdx.x;
  int lane = tid & 63, wid = tid >> 6;
  int wr = wid >> 1, wc = wid & 1;
  int lq = lane & 15, lh = lane >> 4;
  int mb = blockIdx.x * 128;
  int nb = blockIdx.y << 7;

  int srow = (wid << 5) + (lane >> 2);
  int scol = (lane & 3) << 3;
  const unsigned short* Ag = A + (size_t)(mb + srow) * Dd + scol;
  const unsigned short* Bg0 = BtQ + (size_t)(nb + srow) * Dd + scol;
  const unsigned short* Bg1 = BtK + (size_t)(nb + srow) * Dd + scol;
  const unsigned short* Bg2 = BtV + (size_t)(nb + srow) * Dd + scol;
  unsigned short* Alw = Al + (wid << 10);
  unsigned short* Blw0 = &Bl[0][0] + (wid << 10);
  unsigned short* Blw1 = &Bl[1][0] + (wid << 10);
  unsigned short* Blw2 = &Bl[2][0] + (wid << 10);

  f32x4 zero = {0.f, 0.f, 0.f, 0.f};
  f32x4 acc[3][4][4];
#pragma unroll
  for (int s = 0; s < 3; s++)
#pragma unroll
    for (int m = 0; m < 4; m++)
#pragma unroll
      for (int n = 0; n < 4; n++) acc[s][m][n] = zero;

  for (int kb = 0; kb < Dd; kb += 32) {
    __syncthreads();
    gload_lds16(Ag + kb, Alw);
    gload_lds16(Ag + kb + 16 * Dd, Alw + 16 * 32);
    gload_lds16(Bg0 + kb, Blw0);
    gload_lds16(Bg0 + kb + 16 * Dd, Blw0 + 16 * 32);
    gload_lds16(Bg1 + kb, Blw1);
    gload_lds16(Bg1 + kb + 16 * Dd, Blw1 + 16 * 32);
    gload_lds16(Bg2 + kb, Blw2);
    gload_lds16(Bg2 + kb + 16 * Dd, Blw2 + 16 * 32);
    __syncthreads();
    bf16x8 af[4];
#pragma unroll
    for (int m = 0; m < 4; m++)
      af[m] = *(const bf16x8*)(Al + (((wr << 6) + (m << 4) + lq) << 5) + (lh << 3));
#pragma unroll
    for (int s = 0; s < 3; s++) {
      bf16x8 bf[4];
#pragma unroll
      for (int n = 0; n < 4; n++)
        bf[n] = *(const bf16x8*)(&Bl[s][0] +
                                 (((wc << 6) + (n << 4) + lq) << 5) + (lh << 3));
      __builtin_amdgcn_s_setprio(1);
#pragma unroll
      for (int m = 0; m < 4; m++)
#pragma unroll
        for (int n = 0; n < 4; n++) acc[s][m][n] = MFMA(af[m], bf[n], acc[s][m][n]);
      __builtin_amdgcn_s_setprio(0);
    }
  }

  int b_idx = mb >> 11;
#pragma unroll
  for (int s = 0; s < 3; s++) {
#pragma unroll
    for (int n = 0; n < 4; n++) {
      int col = nb + (wc << 6) + (n << 4) + lq;
      float bbias = (s == 0) ? bq[col] : (s == 1) ? bk[col] : bv[col];
      int hh = col >> 6, hd = col & 63;
#pragma unroll
      for (int m = 0; m < 4; m++) {
        int row0 = mb + (wr << 6) + (m << 4) + (lh << 2);
        int t0 = row0 & 2047;
        if (s == 2) {          // V -> [B,H,64,T], t-swizzled
          float v0 = acc[s][m][n][0] + bbias, v1 = acc[s][m][n][1] + bbias;
          float v2 = acc[s][m][n][2] + bbias, v3 = acc[s][m][n][3] + bbias;
          uint2 pv;
          pv.x = f2b(v0) | ((uint32_t)f2b(v1) << 16);
          pv.y = f2b(v2) | ((uint32_t)f2b(v3) << 16);
          int t0s = t0 ^ ((hd & 7) << 3);
          *(uint2*)(VTb + ((size_t)(b_idx * 16 + hh) * 64 + hd) * Tt + t0s) = pv;
        } else {               // Q (scaled) / K (row-swizzled) -> [B,H,T,64]
          unsigned short* O = (s == 0) ? Qb : Kb;
          float sc = (s == 0) ? (0.125f * LOG2E) : 1.0f;
#pragma unroll
          for (int r = 0; r < 4; r++) {
            float v = (acc[s][m][n][r] + bbias) * sc;
            int trow = t0 + r;
            int hds = (s == 0) ? hd : (hd ^ ((trow & 7) << 3));
            O[((size_t)(b_idx * 16 + hh) * Tt + trow) * 64 + hds] = f2b(v);
          }
        }
      }
    }
  }
}

// ---------------- GEMM (projection): A[M][1024] bf16 @ Bt^T + bias -> f32 ----
__global__ __launch_bounds__(256) void k_gemm(
    const unsigned short* __restrict__ A,
    const unsigned short* __restrict__ Bt0,
    const float* __restrict__ bias0,
    float* __restrict__ Pout) {
  __shared__ __align__(16) unsigned short Al[128 * 32];
  __shared__ __align__(16) unsigned short Bl[128 * 32];
  int tid = threadIdx.x;
  int lane = tid & 63, wid = tid >> 6;
  int wr = wid >> 1, wc = wid & 1;
  int lq = lane & 15, lh = lane >> 4;
  int mb = blockIdx.x * 128;
  int nb = blockIdx.y << 7;
  const unsigned short* Bt = Bt0; const float* bias = bias0;

  int srow = (wid << 5) + (lane >> 2);
  int scol = (lane & 3) << 3;
  const unsigned short* Ag = A + (size_t)(mb + srow) * Dd + scol;
  const unsigned short* Bg = Bt + (size_t)(nb + srow) * Dd + scol;
  unsigned short* Alw = Al + (wid << 10);
  unsigned short* Blw = Bl + (wid << 10);

  f32x4 zero = {0.f, 0.f, 0.f, 0.f};
  f32x4 acc[4][4];
#pragma unroll
  for (int m = 0; m < 4; m++)
#pragma unroll
    for (int n = 0; n < 4; n++) acc[m][n] = zero;

  for (int kb = 0; kb < Dd; kb += 32) {
    __syncthreads();
    gload_lds16(Ag + kb, Alw);
    gload_lds16(Ag + kb + 16 * Dd, Alw + 16 * 32);
    gload_lds16(Bg + kb, Blw);
    gload_lds16(Bg + kb + 16 * Dd, Blw + 16 * 32);
    __syncthreads();
    bf16x8 af[4], bf[4];
#pragma unroll
    for (int m = 0; m < 4; m++)
      af[m] = *(const bf16x8*)(Al + (((wr << 6) + (m << 4) + lq) << 5) + (lh << 3));
#pragma unroll
    for (int n = 0; n < 4; n++)
      bf[n] = *(const bf16x8*)(Bl + (((wc << 6) + (n << 4) + lq) << 5) + (lh << 3));
#pragma unroll
    for (int m = 0; m < 4; m++)
#pragma unroll
      for (int n = 0; n < 4; n++) acc[m][n] = MFMA(af[m], bf[n], acc[m][n]);
  }

#pragma unroll
  for (int n = 0; n < 4; n++) {
    int col = nb + (wc << 6) + (n << 4) + lq;
    float bb = bias[col];
#pragma unroll
    for (int m = 0; m < 4; m++) {
      int row0 = mb + (wr << 6) + (m << 4) + (lh << 2);
#pragma unroll
      for (int r = 0; r < 4; r++)
        Pout[(size_t)(row0 + r) * Dd + col] = acc[m][n][r] + bb;
    }
  }
}

// ---------------- flash attention (causal), Q pre-scaled by 0.125*log2e ----------
// r13 structure (proven 75us, cap 256 via (256,2)) with 128-row KV tiles:
// per-tile compute doubles (staging latency fully hidden), barrier count
// halves (2qt+3 vs 4qt+5), fully-masked diagonal sub-blocks skipped.
// LDS 64KB (2x (16K K + 16K V)) -> 2 blocks/CU (thread-limited anyway).
__global__ __launch_bounds__(256, 2) void k_attn(
    const unsigned short* __restrict__ Qb, const unsigned short* __restrict__ Kb,
    const unsigned short* __restrict__ VTb, unsigned short* __restrict__ yb) {
  __shared__ __align__(16) unsigned short KL[2][8192];  // 128 kv rows x 64 hd
  __shared__ __align__(16) unsigned short VL[2][8192];  // 64 hd rows x 128 t
  int b = blockIdx.x;
  int qt = (b < 256) ? (7 - (b >> 6)) : ((b - 256) >> 6);
  int rr6 = b & 63;
  int bh = ((rr6 & 7) << 3) | (rr6 >> 3);    // XCD x holds heads 8x..8x+7
  int tid = threadIdx.x, lane = tid & 63, w = tid >> 6;
  int l31 = lane & 31, hi = lane >> 5;
  const unsigned short* __restrict__ Qh = Qb + (size_t)bh * Tt * 64;
  const unsigned short* __restrict__ Kh = Kb + (size_t)bh * Tt * 64;
  const unsigned short* __restrict__ Vh = VTb + (size_t)bh * 64 * Tt;
  int qgA = (qt << 8) + (w << 6);            // wave's 64 q rows (two halves)
  int qgB = qgA + 32;

  bf16x8 qfA[4], qfB[4];
#pragma unroll
  for (int c = 0; c < 4; c++) {
    qfA[c] = *(const bf16x8*)(Qh + (size_t)(qgA + l31) * 64 + (c << 4) + (hi << 3));
    qfB[c] = *(const bf16x8*)(Qh + (size_t)(qgB + l31) * 64 + (c << 4) + (hi << 3));
  }

  f32x16 accA0, accA1, accB0, accB1;
#pragma unroll
  for (int i = 0; i < 16; i++) { accA0[i] = 0.f; accA1[i] = 0.f; accB0[i] = 0.f; accB1[i] = 0.f; }
  float lsumA = 0.f, lsumB = 0.f;

  int jmaxb = (qt << 1) + 1;   // 128-row kv tiles: 0..jmaxb covers q-tile diag
  int srowK = lane >> 3, scolK = (lane & 7) << 3;
  int rowbK = w << 5;          // wave stages 32 K rows per tile
  int srowV = lane >> 4, scolV = (lane & 15) << 3;
  int rowbV = w << 4;          // wave stages 16 V rows (x128 t) per tile
  int swz = l31 & 7;

#define STAGE(kvt_, bi_) do {                                                        \
    int kv_ = (kvt_) << 7;                                                           \
    gload_lds16(Kh + (size_t)(kv_ + rowbK + srowK) * 64 + scolK,                     \
                &KL[bi_][rowbK << 6]);                                               \
    gload_lds16(Kh + (size_t)(kv_ + rowbK + 8 + srowK) * 64 + scolK,                 \
                &KL[bi_][(rowbK + 8) << 6]);                                         \
    gload_lds16(Kh + (size_t)(kv_ + rowbK + 16 + srowK) * 64 + scolK,                \
                &KL[bi_][(rowbK + 16) << 6]);                                        \
    gload_lds16(Kh + (size_t)(kv_ + rowbK + 24 + srowK) * 64 + scolK,                \
                &KL[bi_][(rowbK + 24) << 6]);                                        \
    gload_lds16(Vh + (size_t)(rowbV + srowV) * Tt + kv_ + scolV,                     \
                &VL[bi_][rowbV << 7]);                                               \
    gload_lds16(Vh + (size_t)(rowbV + 4 + srowV) * Tt + kv_ + scolV,                 \
                &VL[bi_][(rowbV + 4) << 7]);                                         \
    gload_lds16(Vh + (size_t)(rowbV + 8 + srowV) * Tt + kv_ + scolV,                 \
                &VL[bi_][(rowbV + 8) << 7]);                                         \
    gload_lds16(Vh + (size_t)(rowbV + 12 + srowV) * Tt + kv_ + scolV,                \
                &VL[bi_][(rowbV + 12) << 7]);                                        \
  } while (0)

  STAGE(0, 0);
  __syncthreads();

  int cur = 0;
  for (int jt = 0; jt <= jmaxb; ++jt) {
    if (jt < jmaxb) STAGE(jt + 1, cur ^ 1);  // latency hides under 2x compute
    int base_kv = jt << 7;
    if (qgB >= base_kv) {
      const unsigned short* KB = &KL[cur][0];
      const unsigned short* VB = &VL[cur][0];
#pragma unroll
      for (int n2 = 0; n2 < 4; n2++) {
        int rel_base = qgA - base_kv - (n2 << 5);   // wave-uniform, mult of 32
        if (rel_base >= -32) {                      // kv sub-block <= qgB
          bf16x8 kf[4];
          int krowb = ((n2 << 5) + l31) << 6;
#pragma unroll
          for (int c = 0; c < 4; c++)
            kf[c] = *(const bf16x8*)(KB + krowb + ((((c << 1) + hi) ^ swz) << 3));
          f32x16 sA, sB;
#pragma unroll
          for (int i = 0; i < 16; i++) { sA[i] = 0.f; sB[i] = 0.f; }
          __builtin_amdgcn_s_setprio(1);
#pragma unroll
          for (int c = 0; c < 4; c++) {
            sA = MFMA32(kf[c], qfA[c], sA);
            sB = MFMA32(kf[c], qfB[c], sB);
          }
          __builtin_amdgcn_s_setprio(0);
          float pA[16], pB[16];
          if (rel_base <= 0) {   // diagonal / fully-masked-A sub-block
            int relA = rel_base + l31, relB = relA + 32;
#pragma unroll
            for (int r = 0; r < 16; r++) {
              int krow = (r & 3) + ((r >> 2) << 3) + (hi << 2);
              pA[r] = EXP2(krow > relA ? -1e30f : sA[r]);
              pB[r] = EXP2(krow > relB ? -1e30f : sB[r]);
            }
          } else {
#pragma unroll
            for (int r = 0; r < 16; r++) { pA[r] = EXP2(sA[r]); pB[r] = EXP2(sB[r]); }
          }
          lsumA += (((pA[0] + pA[1]) + (pA[2] + pA[3])) + ((pA[4] + pA[5]) + (pA[6] + pA[7])))
                 + (((pA[8] + pA[9]) + (pA[10] + pA[11])) + ((pA[12] + pA[13]) + (pA[14] + pA[15])));
          lsumB += (((pB[0] + pB[1]) + (pB[2] + pB[3])) + ((pB[4] + pB[5]) + (pB[6] + pB[7])))
                 + (((pB[8] + pB[9]) + (pB[10] + pB[11])) + ((pB[12] + pB[13]) + (pB[14] + pB[15])));
          vfu vf[2][2];
#pragma unroll
          for (int n2v = 0; n2v < 2; n2v++) {
            int vrowb = ((n2v << 5) + l31) << 7;   // V row stride = 128 t
#pragma unroll
            for (int cc = 0; cc < 2; cc++) {
              int blk0 = (n2 << 2) + (cc << 1);    // t-block in [0,15]
              vf[n2v][cc].u2[0] =
                  *(const uint2*)(VB + vrowb + ((blk0 ^ swz) << 3) + (hi << 2));
              vf[n2v][cc].u2[1] =
                  *(const uint2*)(VB + vrowb + (((blk0 + 1) ^ swz) << 3) + (hi << 2));
            }
          }
          apu a0, a1, b0, b1;
#pragma unroll
          for (int g = 0; g < 4; g++) {
            a0.u[g] = pk2(pA[2 * g], pA[2 * g + 1]);
            a1.u[g] = pk2(pA[8 + 2 * g], pA[8 + 2 * g + 1]);
            b0.u[g] = pk2(pB[2 * g], pB[2 * g + 1]);
            b1.u[g] = pk2(pB[8 + 2 * g], pB[8 + 2 * g + 1]);
          }
          __builtin_amdgcn_s_setprio(1);
          accA0 = MFMA32(a0.v, vf[0][0].v, accA0);
          accA1 = MFMA32(a0.v, vf[1][0].v, accA1);
          accB0 = MFMA32(b0.v, vf[0][0].v, accB0);
          accB1 = MFMA32(b0.v, vf[1][0].v, accB1);
          accA0 = MFMA32(a1.v, vf[0][1].v, accA0);
          accA1 = MFMA32(a1.v, vf[1][1].v, accA1);
          accB0 = MFMA32(b1.v, vf[0][1].v, accB0);
          accB1 = MFMA32(b1.v, vf[1][1].v, accB1);
          __builtin_amdgcn_s_setprio(0);
        }
      }
    }
    __syncthreads();
    cur ^= 1;
  }
#undef STAGE

  lsumA += __shfl_xor(lsumA, 32);
  lsumB += __shfl_xor(lsumB, 32);
  float invA = 1.0f / lsumA;
  float invB = 1.0f / lsumB;
  int bb = bh >> 4, hh = bh & 15;
#pragma unroll
  for (int r = 0; r < 16; r++) {
    int qr = (r & 3) + ((r >> 2) << 3) + (hi << 2);
    float invqA = __shfl(invA, qr);
    float invqB = __shfl(invB, qr);
    size_t baseA = ((size_t)(bb * Tt + qgA + qr)) * Dd + (hh << 6) + l31;
    size_t baseB = ((size_t)(bb * Tt + qgB + qr)) * Dd + (hh << 6) + l31;
    yb[baseA] = f2b(accA0[r] * invqA);
    yb[baseA + 32] = f2b(accA1[r] * invqA);
    yb[baseB] = f2b(accB0[r] * invqB);
    yb[baseB + 32] = f2b(accB1[r] * invqB);
  }
}

extern "C" void kernel_launch(void* const* d_in, const int* in_sizes, int n_in,
                              void* d_out, int out_size, void* d_ws, size_t ws_size,
                              hipStream_t stream) {
  const float* x = (const float*)d_in[0];
  const float* Wk = (const float*)d_in[1];
  const float* bk = (const float*)d_in[2];
  const float* Wq = (const float*)d_in[3];
  const float* bq = (const float*)d_in[4];
  const float* Wv = (const float*)d_in[5];
  const float* bv = (const float*)d_in[6];
  const float* Wp = (const float*)d_in[7];
  const float* bp = (const float*)d_in[8];
  float* out = (float*)d_out;

  char* ws = (char*)d_ws;
  unsigned short* xb  = (unsigned short*)(ws);                       // 16MB
  unsigned short* WkT = (unsigned short*)(ws + (16ull << 20));       // 2MB each
  unsigned short* WqT = (unsigned short*)(ws + (18ull << 20));
  unsigned short* WvT = (unsigned short*)(ws + (20ull << 20));
  unsigned short* WpT = (unsigned short*)(ws + (22ull << 20));
  unsigned short* Qb  = (unsigned short*)(ws + (24ull << 20));       // 16MB
  unsigned short* Kb  = (unsigned short*)(ws + (40ull << 20));       // 16MB
  unsigned short* VTb = (unsigned short*)(ws + (56ull << 20));       // 16MB
  unsigned short* yb  = (unsigned short*)(ws + (72ull << 20));       // 16MB (ends 88MB)

  k_convert_x<<<4096, 256, 0, stream>>>(x, xb);
  k_transpose_w<<<dim3(1024, 4), 256, 0, stream>>>(Wk, Wq, Wv, Wp, WkT, WqT, WvT, WpT);
  k_gemm3<<<dim3(64, 8), 256, 0, stream>>>(xb, WqT, WkT, WvT, bq, bk, bv,
                                           Qb, Kb, VTb);
  k_attn<<<512, 256, 0, stream>>>(Qb, Kb, VTb, yb);
  k_gemm<<<dim3(64, 8), 256, 0, stream>>>(yb, WpT, bp, out);
}